// Round 1
// baseline (767.351 us; speedup 1.0000x reference)
//
#include <hip/hip_runtime.h>
#include <hip/hip_bf16.h>
#include <cstdint>
#include <cstddef>

typedef __attribute__((ext_vector_type(8))) short short8;
typedef __attribute__((ext_vector_type(4))) float f32x4;
typedef unsigned short u16;

static __device__ __forceinline__ u16 f2bf(float f) {
  __hip_bfloat16 h = __float2bfloat16(f);
  return *reinterpret_cast<u16*>(&h);
}

static __device__ __forceinline__ void gload16(const void* g, void* l) {
  __builtin_amdgcn_global_load_lds(
      (const __attribute__((address_space(1))) void*)g,
      (__attribute__((address_space(3))) void*)l, 16, 0, 0);
}

// ---------------- prep kernels ----------------

__global__ void cast_k(const float* __restrict__ in, u16* __restrict__ out, int n4) {
  int i = blockIdx.x * 256 + threadIdx.x;
  if (i < n4) {
    float4 v = ((const float4*)in)[i];
    union { u16 u[4]; uint2 p; } r;
    r.u[0] = f2bf(v.x); r.u[1] = f2bf(v.y); r.u[2] = f2bf(v.z); r.u[3] = f2bf(v.w);
    ((uint2*)out)[i] = r.p;
  }
}

// in_t[b][s][i] = bf16( concat(x1,x2)[b][i][s] ), i in [0,2048)
__global__ void build_int(const float* __restrict__ x1, const float* __restrict__ x2,
                          u16* __restrict__ in_t) {
  __shared__ float tile[64][65];
  const int it = blockIdx.x;   // 32 i-tiles
  const int st = blockIdx.y;   // 16 s-tiles
  const int b  = blockIdx.z;   // 8
  const int i0 = it * 64, s0 = st * 64;
  const float* src = (i0 < 1024)
      ? x1 + ((size_t)b * 1024 + i0) * 1024
      : x2 + ((size_t)b * 1024 + (i0 - 1024)) * 1024;
  const int t = threadIdx.x;
  #pragma unroll
  for (int jj = 0; jj < 16; ++jj) {
    int idx = jj * 256 + t;
    int ii = idx >> 6, si = idx & 63;
    tile[ii][si] = src[(size_t)ii * 1024 + s0 + si];
  }
  __syncthreads();
  #pragma unroll
  for (int jj = 0; jj < 16; ++jj) {
    int idx = jj * 256 + t;
    int si = idx >> 6, ii = idx & 63;
    in_t[((size_t)b * 1024 + s0 + si) * 2048 + i0 + ii] = f2bf(tile[ii][si]);
  }
}

// Wp[q][o][i] = bf16( conv_w[o][i][q] ),  q = ky*3+kx
__global__ void pack_wp(const float* __restrict__ cw, u16* __restrict__ Wp) {
  __shared__ float sb[2304];
  const int blk = blockIdx.x;  // 8192
  const int t = threadIdx.x;   // 256
  const size_t base = (size_t)blk * 2304;
  #pragma unroll
  for (int jj = 0; jj < 9; ++jj) sb[jj * 256 + t] = cw[base + jj * 256 + t];
  __syncthreads();
  const int p = blk * 256 + t;  // (o,i) linear
  #pragma unroll
  for (int q = 0; q < 9; ++q)
    Wp[(size_t)q * 2097152 + p] = f2bf(sb[t * 9 + q]);
}

__global__ void zero_k(u16* z) { z[threadIdx.x] = 0; }

// ---------------- GEMM (C = A @ B^T), 128x128 tile, BK=64 ----------------

enum { GM_PLAIN = 0, GM_VT = 1, GM_PROJ = 2, GM_CONV = 3 };

template<int MODE>
__global__ __launch_bounds__(256, 2)
void gemm_k(const u16* __restrict__ A, const u16* __restrict__ B,
            u16* __restrict__ Cb, float* __restrict__ Cf,
            const float* __restrict__ bias, const float* __restrict__ resid,
            const u16* __restrict__ zb, int Ktot) {
  __shared__ u16 As[128 * 64];
  __shared__ u16 Bs[128 * 64];
  const int tid = threadIdx.x;
  const int lane = tid & 63;
  const int w = tid >> 6;
  const int tn = blockIdx.x, tm = blockIdx.y;
  const int row0 = tm * 128, col0 = tn * 128;
  const int l15 = lane & 15, l4 = lane >> 4;

  f32x4 acc[4][4];
  #pragma unroll
  for (int i = 0; i < 4; ++i)
    #pragma unroll
    for (int jj = 0; jj < 4; ++jj)
      acc[i][jj] = (f32x4){0.f, 0.f, 0.f, 0.f};

  const int nK = Ktot >> 6;
  for (int kt = 0; kt < nK; ++kt) {
    const int k0 = kt << 6;
    __syncthreads();
    // stage A (128 x 64 bf16)
    #pragma unroll
    for (int j = 0; j < 4; ++j) {
      const int c = (j * 4 + w) * 64 + lane;
      const int r = c >> 3;
      const int coff = (c & 7) << 3;
      const u16* gp;
      if constexpr (MODE == GM_CONV) {
        const int q = k0 >> 11;           // kernel-offset segment 0..8
        const int ks = k0 & 2047;         // channel within segment
        const int qd = q / 3;
        const int dy = qd - 1, dx = q - qd * 3 - 1;
        const int m = row0 + r;
        const int b = m >> 10, s = m & 1023;
        const int y = s >> 5, x = s & 31;
        const int yy = y + dy, xx = x + dx;
        const bool valid = ((unsigned)yy < 32u) && ((unsigned)xx < 32u);
        gp = valid ? (A + (((size_t)((b << 10) + (yy << 5) + xx)) << 11) + ks + coff)
                   : zb;
      } else {
        gp = A + (size_t)(row0 + r) * Ktot + k0 + coff;
      }
      gload16(gp, (void*)(As + (j * 4 + w) * 512));
    }
    // stage B (128 x 64 bf16), B is [ncols][K] row-major
    #pragma unroll
    for (int j = 0; j < 4; ++j) {
      const int c = (j * 4 + w) * 64 + lane;
      const int r = c >> 3;
      const int coff = (c & 7) << 3;
      const u16* gp;
      if constexpr (MODE == GM_CONV) {
        const int q = k0 >> 11;
        const int ks = k0 & 2047;
        gp = B + ((size_t)q << 21) + ((size_t)(col0 + r) << 11) + ks + coff;
      } else {
        gp = B + (size_t)(col0 + r) * Ktot + k0 + coff;
      }
      gload16(gp, (void*)(Bs + (j * 4 + w) * 512));
    }
    __syncthreads();
    const int wr = (w >> 1) << 6, wc = (w & 1) << 6;
    #pragma unroll
    for (int ks2 = 0; ks2 < 2; ++ks2) {
      const int koff = (ks2 << 5) + (l4 << 3);
      short8 av[4], bv[4];
      #pragma unroll
      for (int i = 0; i < 4; ++i)
        av[i] = *(const short8*)(As + (wr + i * 16 + l15) * 64 + koff);
      #pragma unroll
      for (int i = 0; i < 4; ++i)
        bv[i] = *(const short8*)(Bs + (wc + i * 16 + l15) * 64 + koff);
      #pragma unroll
      for (int mi = 0; mi < 4; ++mi)
        #pragma unroll
        for (int ni = 0; ni < 4; ++ni)
          acc[mi][ni] = __builtin_amdgcn_mfma_f32_16x16x32_bf16(av[mi], bv[ni], acc[mi][ni], 0, 0, 0);
    }
  }
  // epilogue: D layout col=lane&15, row=(lane>>4)*4+j  (m89-verified)
  const int wr = (w >> 1) << 6, wc = (w & 1) << 6;
  #pragma unroll
  for (int mi = 0; mi < 4; ++mi) {
    #pragma unroll
    for (int ni = 0; ni < 4; ++ni) {
      #pragma unroll
      for (int j = 0; j < 4; ++j) {
        const int grow = row0 + wr + mi * 16 + l4 * 4 + j;
        const int gcol = col0 + wc + ni * 16 + l15;
        const float v = acc[mi][ni][j];
        if constexpr (MODE == GM_PLAIN) {
          Cb[((size_t)grow << 10) + gcol] = f2bf(v);
        } else if constexpr (MODE == GM_VT) {
          const int b = grow >> 10, ms = grow & 1023;
          const int h = gcol >> 7, d = gcol & 127;
          Cb[((size_t)((b * 8 + h) * 128 + d) << 10) + ms] = f2bf(v);
        } else if constexpr (MODE == GM_PROJ) {
          const size_t o = ((size_t)grow << 10) + gcol;
          Cf[o] = v + bias[gcol] + resid[o];
        } else {  // GM_CONV: xc[b][o][s]
          const int b = grow >> 10, s = grow & 1023;
          Cb[((size_t)((b << 10) + gcol) << 10) + s] = f2bf(v + bias[gcol]);
        }
      }
    }
  }
}

// ---------------- flash attention ----------------
// grid (16 mtiles, 64 bh). 4 waves; wave w owns Q rows [w*16, w*16+16).
__global__ __launch_bounds__(256, 2)
void attn_k(const u16* __restrict__ Q, const u16* __restrict__ K,
            const u16* __restrict__ Vt, u16* __restrict__ O) {
  __shared__ u16 Ks[64 * 128];
  __shared__ u16 Vs[128 * 64];
  __shared__ u16 Plds[4][16 * 80];
  const int mtile = blockIdx.x;
  const int bh = blockIdx.y;
  const int b = bh >> 3, h = bh & 7;
  const int tid = threadIdx.x, lane = tid & 63, w = tid >> 6;
  const int l15 = lane & 15, l4 = lane >> 4;

  // Q fragments held in registers
  short8 qf[4];
  {
    const int qrow = b * 1024 + mtile * 64 + w * 16 + l15;
    const u16* qb = Q + ((size_t)qrow << 10) + h * 128;
    #pragma unroll
    for (int kk = 0; kk < 4; ++kk)
      qf[kk] = *(const short8*)(qb + kk * 32 + l4 * 8);
  }

  f32x4 o[8];
  #pragma unroll
  for (int db = 0; db < 8; ++db) o[db] = (f32x4){0.f, 0.f, 0.f, 0.f};
  float mrow[4], lrow[4];
  #pragma unroll
  for (int j = 0; j < 4; ++j) { mrow[j] = -1e30f; lrow[j] = 0.f; }
  const float scale = 0.08838834764831845f;  // 128^-0.5

  for (int kt = 0; kt < 16; ++kt) {
    __syncthreads();
    // stage K tile [64 m][128 d]
    #pragma unroll
    for (int j = 0; j < 4; ++j) {
      const int c = (j * 4 + w) * 64 + lane;
      const int r = c >> 4, coff = (c & 15) << 3;
      const u16* gp = K + ((size_t)(b * 1024 + kt * 64 + r) << 10) + h * 128 + coff;
      gload16(gp, (void*)(Ks + (j * 4 + w) * 512));
    }
    // stage V tile [128 d][64 m] from Vt
    #pragma unroll
    for (int j = 0; j < 4; ++j) {
      const int c = (j * 4 + w) * 64 + lane;
      const int r = c >> 3, coff = (c & 7) << 3;
      const u16* gp = Vt + ((size_t)((b * 8 + h) * 128 + r) << 10) + kt * 64 + coff;
      gload16(gp, (void*)(Vs + (j * 4 + w) * 512));
    }
    __syncthreads();
    // S = Q K^T  (wave's 16 rows x 64 cols)
    f32x4 s[4];
    #pragma unroll
    for (int cb = 0; cb < 4; ++cb) {
      s[cb] = (f32x4){0.f, 0.f, 0.f, 0.f};
      #pragma unroll
      for (int kk = 0; kk < 4; ++kk) {
        short8 bK = *(const short8*)(Ks + (cb * 16 + l15) * 128 + kk * 32 + l4 * 8);
        s[cb] = __builtin_amdgcn_mfma_f32_16x16x32_bf16(qf[kk], bK, s[cb], 0, 0, 0);
      }
    }
    #pragma unroll
    for (int cb = 0; cb < 4; ++cb) {
      s[cb][0] *= scale; s[cb][1] *= scale; s[cb][2] *= scale; s[cb][3] *= scale;
    }
    // online softmax per row j (row = l4*4+j; reduce across the 16 lanes l15)
    #pragma unroll
    for (int j = 0; j < 4; ++j) {
      float mx = fmaxf(fmaxf(s[0][j], s[1][j]), fmaxf(s[2][j], s[3][j]));
      #pragma unroll
      for (int off = 8; off >= 1; off >>= 1)
        mx = fmaxf(mx, __shfl_xor(mx, off, 64));
      const float mn = fmaxf(mrow[j], mx);
      const float fac = __expf(mrow[j] - mn);
      mrow[j] = mn;
      float rs = 0.f;
      #pragma unroll
      for (int cb = 0; cb < 4; ++cb) {
        const float p = __expf(s[cb][j] - mn);
        s[cb][j] = p;
        rs += p;
      }
      #pragma unroll
      for (int off = 8; off >= 1; off >>= 1)
        rs += __shfl_xor(rs, off, 64);
      lrow[j] = lrow[j] * fac + rs;
      #pragma unroll
      for (int db = 0; db < 8; ++db) o[db][j] *= fac;
    }
    // P -> LDS (per-wave region), D-layout write, A-layout read
    u16* pl = Plds[w];
    #pragma unroll
    for (int cb = 0; cb < 4; ++cb)
      #pragma unroll
      for (int j = 0; j < 4; ++j)
        pl[(l4 * 4 + j) * 80 + cb * 16 + l15] = f2bf(s[cb][j]);
    __syncthreads();
    short8 ap[2];
    #pragma unroll
    for (int ks = 0; ks < 2; ++ks)
      ap[ks] = *(const short8*)(pl + l15 * 80 + ks * 32 + l4 * 8);
    #pragma unroll
    for (int db = 0; db < 8; ++db) {
      #pragma unroll
      for (int ks = 0; ks < 2; ++ks) {
        short8 bV = *(const short8*)(Vs + (db * 16 + l15) * 64 + ks * 32 + l4 * 8);
        o[db] = __builtin_amdgcn_mfma_f32_16x16x32_bf16(ap[ks], bV, o[db], 0, 0, 0);
      }
    }
  }
  // epilogue: O[b*1024+n][h*128+d]
  #pragma unroll
  for (int db = 0; db < 8; ++db) {
    #pragma unroll
    for (int j = 0; j < 4; ++j) {
      const int grow = b * 1024 + mtile * 64 + w * 16 + l4 * 4 + j;
      const int gcol = h * 128 + db * 16 + l15;
      O[((size_t)grow << 10) + gcol] = f2bf(o[db][j] / lrow[j]);
    }
  }
}

// ---------------- launch ----------------

extern "C" void kernel_launch(void* const* d_in, const int* in_sizes, int n_in,
                              void* d_out, int out_size, void* d_ws, size_t ws_size,
                              hipStream_t stream) {
  const float* x1     = (const float*)d_in[0];
  const float* x2     = (const float*)d_in[1];
  const float* conv_w = (const float*)d_in[2];
  const float* conv_b = (const float*)d_in[3];
  const float* wq     = (const float*)d_in[4];
  const float* wk     = (const float*)d_in[5];
  const float* wv     = (const float*)d_in[6];
  const float* proj_w = (const float*)d_in[7];
  const float* proj_b = (const float*)d_in[8];
  float* out = (float*)d_out;

  char* ws = (char*)d_ws;
  size_t off = 0;
  auto alloc = [&](size_t bytes) -> void* {
    void* p = ws + off;
    off += (bytes + 255) & ~(size_t)255;
    return p;
  };
  u16* x1b  = (u16*)alloc(8192ULL * 1024 * 2);
  u16* in_t = (u16*)alloc(8ULL * 1024 * 2048 * 2);
  u16* Wp   = (u16*)alloc(9ULL * 2097152 * 2);
  u16* wqb  = (u16*)alloc(1048576ULL * 2);
  u16* wkb  = (u16*)alloc(1048576ULL * 2);
  u16* wvb  = (u16*)alloc(1048576ULL * 2);
  u16* pjb  = (u16*)alloc(1048576ULL * 2);
  u16* xc   = (u16*)alloc(8192ULL * 1024 * 2);
  u16* Qb   = (u16*)alloc(8192ULL * 1024 * 2);
  u16* Kb   = (u16*)alloc(8192ULL * 1024 * 2);
  u16* Vtb  = (u16*)alloc(8192ULL * 1024 * 2);
  u16* Ob   = (u16*)alloc(8192ULL * 1024 * 2);
  u16* zb   = (u16*)alloc(256);

  // prep
  cast_k<<<8192, 256, 0, stream>>>(x1, x1b, 2097152);
  cast_k<<<1024, 256, 0, stream>>>(wq, wqb, 262144);
  cast_k<<<1024, 256, 0, stream>>>(wk, wkb, 262144);
  cast_k<<<1024, 256, 0, stream>>>(wv, wvb, 262144);
  cast_k<<<1024, 256, 0, stream>>>(proj_w, pjb, 262144);
  build_int<<<dim3(32, 16, 8), 256, 0, stream>>>(x1, x2, in_t);
  pack_wp<<<8192, 256, 0, stream>>>(conv_w, Wp);
  zero_k<<<1, 128, 0, stream>>>(zb);

  // conv as implicit GEMM (9 shifted segments over K=18432)
  gemm_k<GM_CONV><<<dim3(8, 64), 256, 0, stream>>>(in_t, Wp, xc, nullptr, conv_b, nullptr, zb, 18432);
  // Q/K/V
  gemm_k<GM_PLAIN><<<dim3(8, 64), 256, 0, stream>>>(x1b, wqb, Qb, nullptr, nullptr, nullptr, zb, 1024);
  gemm_k<GM_PLAIN><<<dim3(8, 64), 256, 0, stream>>>(xc, wkb, Kb, nullptr, nullptr, nullptr, zb, 1024);
  gemm_k<GM_VT><<<dim3(8, 64), 256, 0, stream>>>(xc, wvb, Vtb, nullptr, nullptr, nullptr, zb, 1024);
  // attention
  attn_k<<<dim3(16, 64), 256, 0, stream>>>(Qb, Kb, Vtb, Ob);
  // projection + bias + residual (f32 out)
  gemm_k<GM_PROJ><<<dim3(8, 64), 256, 0, stream>>>(Ob, pjb, nullptr, out, proj_b, x1, zb, 1024);
}

// Round 2
// 653.555 us; speedup vs baseline: 1.1741x; 1.1741x over previous
//
#include <hip/hip_runtime.h>
#include <hip/hip_bf16.h>
#include <cstdint>
#include <cstddef>

typedef __attribute__((ext_vector_type(8))) short short8;
typedef __attribute__((ext_vector_type(4))) float f32x4;
typedef unsigned short u16;

static __device__ __forceinline__ u16 f2bf(float f) {
  __hip_bfloat16 h = __float2bfloat16(f);
  return *reinterpret_cast<u16*>(&h);
}

static __device__ __forceinline__ void gload16(const void* g, void* l) {
  __builtin_amdgcn_global_load_lds(
      (const __attribute__((address_space(1))) void*)g,
      (__attribute__((address_space(3))) void*)l, 16, 0, 0);
}

// ---------------- prep kernels ----------------

__global__ void cast_k(const float* __restrict__ in, u16* __restrict__ out, int n4) {
  int i = blockIdx.x * 256 + threadIdx.x;
  if (i < n4) {
    float4 v = ((const float4*)in)[i];
    union { u16 u[4]; uint2 p; } r;
    r.u[0] = f2bf(v.x); r.u[1] = f2bf(v.y); r.u[2] = f2bf(v.z); r.u[3] = f2bf(v.w);
    ((uint2*)out)[i] = r.p;
  }
}

// in_t[b][s][i] = bf16( concat(x1,x2)[b][i][s] ), i in [0,2048)
__global__ void build_int(const float* __restrict__ x1, const float* __restrict__ x2,
                          u16* __restrict__ in_t) {
  __shared__ float tile[64][65];
  const int it = blockIdx.x;   // 32 i-tiles
  const int st = blockIdx.y;   // 16 s-tiles
  const int b  = blockIdx.z;   // 8
  const int i0 = it * 64, s0 = st * 64;
  const float* src = (i0 < 1024)
      ? x1 + ((size_t)b * 1024 + i0) * 1024
      : x2 + ((size_t)b * 1024 + (i0 - 1024)) * 1024;
  const int t = threadIdx.x;
  #pragma unroll
  for (int jj = 0; jj < 16; ++jj) {
    int idx = jj * 256 + t;
    int ii = idx >> 6, si = idx & 63;
    tile[ii][si] = src[(size_t)ii * 1024 + s0 + si];
  }
  __syncthreads();
  #pragma unroll
  for (int jj = 0; jj < 16; ++jj) {
    int idx = jj * 256 + t;
    int si = idx >> 6, ii = idx & 63;
    in_t[((size_t)b * 1024 + s0 + si) * 2048 + i0 + ii] = f2bf(tile[ii][si]);
  }
}

// Wp[q][o][i] = bf16( conv_w[o][i][q] ),  q = ky*3+kx
__global__ void pack_wp(const float* __restrict__ cw, u16* __restrict__ Wp) {
  __shared__ float sb[2304];
  const int blk = blockIdx.x;  // 8192
  const int t = threadIdx.x;   // 256
  const size_t base = (size_t)blk * 2304;
  #pragma unroll
  for (int jj = 0; jj < 9; ++jj) sb[jj * 256 + t] = cw[base + jj * 256 + t];
  __syncthreads();
  const int p = blk * 256 + t;  // (o,i) linear
  #pragma unroll
  for (int q = 0; q < 9; ++q)
    Wp[(size_t)q * 2097152 + p] = f2bf(sb[t * 9 + q]);
}

__global__ void zero_k(u16* z) { z[threadIdx.x] = 0; }

// ---------------- pipelined GEMM (C = A @ B^T), 128x128 tile, BK=64 ----------------
// 512 threads = 8 waves (2M x 4N), wave owns 64x32. Triple-buffered LDS (96 KiB),
// counted vmcnt(4) (T3+T4), XOR-swizzled LDS cols (T2, rule #21: linear dest +
// inverse-swizzled source + swizzled read), setprio on MFMA (T5).

enum { GM_PLAIN = 0, GM_VT = 1, GM_PROJ = 2, GM_CONV = 3 };

template<int MODE>
__global__ __launch_bounds__(512, 2)
void gemm2_k(const u16* __restrict__ A, const u16* __restrict__ B,
             u16* __restrict__ Cb, float* __restrict__ Cf,
             const float* __restrict__ bias, const float* __restrict__ resid,
             const u16* __restrict__ zb, int Ktot) {
  __shared__ u16 lds[3 * 16384];  // per buf: A 128x64 (8192 u16) + B 128x64
  const int tid = threadIdx.x;
  const int lane = tid & 63;
  const int w = tid >> 6;
  const int l15 = lane & 15, l4 = lane >> 4;

  // T1: chunked XCD remap (nwg=512, 512%8==0 -> bijective)
  const int bid = blockIdx.x;
  const int lb = (bid & 7) * 64 + (bid >> 3);
  const int tm = lb >> 3, tn = lb & 7;
  const int row0 = tm * 128, col0 = tn * 128;
  const int wr = (w >> 2) * 64, wc = (w & 3) * 32;

  // staging geometry: chunk c = u*512 + w*64 + lane; row r = u*64 + w*8 + (lane>>3)
  const int sr = w * 8 + (lane >> 3);
  const int pp = (lane & 7) ^ (lane >> 3);   // inverse-swizzled 16B chunk col

  // conv A-row precompute (r = u*64 + sr)
  int am[2], ay[2], ax[2];
  #pragma unroll
  for (int u = 0; u < 2; ++u) {
    const int m = row0 + u * 64 + sr;
    am[u] = m;
    const int s = m & 1023;
    ay[u] = s >> 5; ax[u] = s & 31;
  }

  f32x4 acc[4][2];
  #pragma unroll
  for (int i = 0; i < 4; ++i)
    #pragma unroll
    for (int jj = 0; jj < 2; ++jj)
      acc[i][jj] = (f32x4){0.f, 0.f, 0.f, 0.f};

  const int nK = Ktot >> 6;

  auto stage = [&](int kt, u16* buf) {
    u16* da = buf + (size_t)w * 512;          // + u*4096 below
    u16* db = buf + 8192 + (size_t)w * 512;
    if constexpr (MODE == GM_CONV) {
      const int q = kt >> 5;                  // offset plane 0..8
      const int ks = (kt & 31) << 6;
      const int qd = (q >= 6) ? 2 : (q >= 3) ? 1 : 0;
      const int dy = qd - 1, dx = q - qd * 3 - 1;
      const int dd = (dy << 5) + dx;
      const size_t boff = ((size_t)q << 21) + ks + pp * 8;
      #pragma unroll
      for (int u = 0; u < 2; ++u) {
        const int yy = ay[u] + dy, xx = ax[u] + dx;
        const bool valid = ((unsigned)yy < 32u) && ((unsigned)xx < 32u);
        const u16* ga = valid ? A + (((size_t)(am[u] + dd)) << 11) + ks + pp * 8 : zb;
        gload16(ga, da + u * 4096);
        const u16* gb = B + boff + ((size_t)(col0 + u * 64 + sr) << 11);
        gload16(gb, db + u * 4096);
      }
    } else {
      const int k0 = kt << 6;
      #pragma unroll
      for (int u = 0; u < 2; ++u) {
        const u16* ga = A + (size_t)(row0 + u * 64 + sr) * Ktot + k0 + pp * 8;
        gload16(ga, da + u * 4096);
        const u16* gb = B + (size_t)(col0 + u * 64 + sr) * Ktot + k0 + pp * 8;
        gload16(gb, db + u * 4096);
      }
    }
  };

  auto compute = [&](const u16* buf) {
    const char* Ar = (const char*)buf;
    const char* Br = (const char*)(buf + 8192);
    #pragma unroll
    for (int ks = 0; ks < 2; ++ks) {
      const int bcol = ((ks << 6) + (l4 << 4)) ^ ((l15 & 7) << 4);
      short8 av[4], bv[2];
      #pragma unroll
      for (int mi = 0; mi < 4; ++mi)
        av[mi] = *(const short8*)(Ar + (wr + mi * 16 + l15) * 128 + bcol);
      #pragma unroll
      for (int ni = 0; ni < 2; ++ni)
        bv[ni] = *(const short8*)(Br + (wc + ni * 16 + l15) * 128 + bcol);
      __builtin_amdgcn_s_setprio(1);
      #pragma unroll
      for (int mi = 0; mi < 4; ++mi)
        #pragma unroll
        for (int ni = 0; ni < 2; ++ni)
          acc[mi][ni] = __builtin_amdgcn_mfma_f32_16x16x32_bf16(av[mi], bv[ni], acc[mi][ni], 0, 0, 0);
      __builtin_amdgcn_s_setprio(0);
    }
  };

  u16* pb0 = lds;
  u16* pb1 = lds + 16384;
  u16* pb2 = lds + 32768;

  stage(0, pb0);
  stage(1, pb1);
  for (int t = 0; t < nK; ++t) {
    if (t + 1 < nK) {
      asm volatile("s_waitcnt vmcnt(4)" ::: "memory");
    } else {
      asm volatile("s_waitcnt vmcnt(0)" ::: "memory");
    }
    __builtin_amdgcn_s_barrier();
    asm volatile("" ::: "memory");
    if (t + 2 < nK) stage(t + 2, pb2);
    compute(pb0);
    u16* tmp = pb0; pb0 = pb1; pb1 = pb2; pb2 = tmp;
  }

  // epilogue: D layout col=lane&15, row=(lane>>4)*4+j
  #pragma unroll
  for (int mi = 0; mi < 4; ++mi) {
    #pragma unroll
    for (int ni = 0; ni < 2; ++ni) {
      #pragma unroll
      for (int j = 0; j < 4; ++j) {
        const int grow = row0 + wr + mi * 16 + l4 * 4 + j;
        const int gcol = col0 + wc + ni * 16 + l15;
        const float v = acc[mi][ni][j];
        if constexpr (MODE == GM_PLAIN) {
          Cb[((size_t)grow << 10) + gcol] = f2bf(v);
        } else if constexpr (MODE == GM_VT) {
          const int b = grow >> 10, ms = grow & 1023;
          const int h = gcol >> 7, d = gcol & 127;
          Cb[((size_t)((b * 8 + h) * 128 + d) << 10) + ms] = f2bf(v);
        } else if constexpr (MODE == GM_PROJ) {
          const size_t o = ((size_t)grow << 10) + gcol;
          Cf[o] = v + bias[gcol] + resid[o];
        } else {  // GM_CONV: xc[b][o][s]
          const int b = grow >> 10, s = grow & 1023;
          Cb[((size_t)((b << 10) + gcol) << 10) + s] = f2bf(v + bias[gcol]);
        }
      }
    }
  }
}

// ---------------- flash attention ----------------
// grid (16 mtiles, 64 bh). 4 waves; wave w owns Q rows [w*16, w*16+16).
__global__ __launch_bounds__(256, 2)
void attn_k(const u16* __restrict__ Q, const u16* __restrict__ K,
            const u16* __restrict__ Vt, u16* __restrict__ O) {
  __shared__ u16 Ks[64 * 128];
  __shared__ u16 Vs[128 * 64];
  __shared__ u16 Plds[4][16 * 80];
  const int mtile = blockIdx.x;
  const int bh = blockIdx.y;
  const int b = bh >> 3, h = bh & 7;
  const int tid = threadIdx.x, lane = tid & 63, w = tid >> 6;
  const int l15 = lane & 15, l4 = lane >> 4;

  short8 qf[4];
  {
    const int qrow = b * 1024 + mtile * 64 + w * 16 + l15;
    const u16* qb = Q + ((size_t)qrow << 10) + h * 128;
    #pragma unroll
    for (int kk = 0; kk < 4; ++kk)
      qf[kk] = *(const short8*)(qb + kk * 32 + l4 * 8);
  }

  f32x4 o[8];
  #pragma unroll
  for (int db = 0; db < 8; ++db) o[db] = (f32x4){0.f, 0.f, 0.f, 0.f};
  float mrow[4], lrow[4];
  #pragma unroll
  for (int j = 0; j < 4; ++j) { mrow[j] = -1e30f; lrow[j] = 0.f; }
  const float scale = 0.08838834764831845f;  // 128^-0.5

  for (int kt = 0; kt < 16; ++kt) {
    __syncthreads();
    #pragma unroll
    for (int j = 0; j < 4; ++j) {
      const int c = (j * 4 + w) * 64 + lane;
      const int r = c >> 4, coff = (c & 15) << 3;
      const u16* gp = K + ((size_t)(b * 1024 + kt * 64 + r) << 10) + h * 128 + coff;
      gload16(gp, (void*)(Ks + (j * 4 + w) * 512));
    }
    #pragma unroll
    for (int j = 0; j < 4; ++j) {
      const int c = (j * 4 + w) * 64 + lane;
      const int r = c >> 3, coff = (c & 7) << 3;
      const u16* gp = Vt + ((size_t)((b * 8 + h) * 128 + r) << 10) + kt * 64 + coff;
      gload16(gp, (void*)(Vs + (j * 4 + w) * 512));
    }
    __syncthreads();
    f32x4 s[4];
    #pragma unroll
    for (int cb = 0; cb < 4; ++cb) {
      s[cb] = (f32x4){0.f, 0.f, 0.f, 0.f};
      #pragma unroll
      for (int kk = 0; kk < 4; ++kk) {
        short8 bK = *(const short8*)(Ks + (cb * 16 + l15) * 128 + kk * 32 + l4 * 8);
        s[cb] = __builtin_amdgcn_mfma_f32_16x16x32_bf16(qf[kk], bK, s[cb], 0, 0, 0);
      }
    }
    #pragma unroll
    for (int cb = 0; cb < 4; ++cb) {
      s[cb][0] *= scale; s[cb][1] *= scale; s[cb][2] *= scale; s[cb][3] *= scale;
    }
    #pragma unroll
    for (int j = 0; j < 4; ++j) {
      float mx = fmaxf(fmaxf(s[0][j], s[1][j]), fmaxf(s[2][j], s[3][j]));
      #pragma unroll
      for (int off = 8; off >= 1; off >>= 1)
        mx = fmaxf(mx, __shfl_xor(mx, off, 64));
      const float mn = fmaxf(mrow[j], mx);
      const float fac = __expf(mrow[j] - mn);
      mrow[j] = mn;
      float rs = 0.f;
      #pragma unroll
      for (int cb = 0; cb < 4; ++cb) {
        const float p = __expf(s[cb][j] - mn);
        s[cb][j] = p;
        rs += p;
      }
      #pragma unroll
      for (int off = 8; off >= 1; off >>= 1)
        rs += __shfl_xor(rs, off, 64);
      lrow[j] = lrow[j] * fac + rs;
      #pragma unroll
      for (int db = 0; db < 8; ++db) o[db][j] *= fac;
    }
    u16* pl = Plds[w];
    #pragma unroll
    for (int cb = 0; cb < 4; ++cb)
      #pragma unroll
      for (int j = 0; j < 4; ++j)
        pl[(l4 * 4 + j) * 80 + cb * 16 + l15] = f2bf(s[cb][j]);
    __syncthreads();
    short8 ap[2];
    #pragma unroll
    for (int ks = 0; ks < 2; ++ks)
      ap[ks] = *(const short8*)(pl + l15 * 80 + ks * 32 + l4 * 8);
    #pragma unroll
    for (int db = 0; db < 8; ++db) {
      #pragma unroll
      for (int ks = 0; ks < 2; ++ks) {
        short8 bV = *(const short8*)(Vs + (db * 16 + l15) * 64 + ks * 32 + l4 * 8);
        o[db] = __builtin_amdgcn_mfma_f32_16x16x32_bf16(ap[ks], bV, o[db], 0, 0, 0);
      }
    }
  }
  #pragma unroll
  for (int db = 0; db < 8; ++db) {
    #pragma unroll
    for (int j = 0; j < 4; ++j) {
      const int grow = b * 1024 + mtile * 64 + w * 16 + l4 * 4 + j;
      const int gcol = h * 128 + db * 16 + l15;
      O[((size_t)grow << 10) + gcol] = f2bf(o[db][j] / lrow[j]);
    }
  }
}

// ---------------- launch ----------------

extern "C" void kernel_launch(void* const* d_in, const int* in_sizes, int n_in,
                              void* d_out, int out_size, void* d_ws, size_t ws_size,
                              hipStream_t stream) {
  const float* x1     = (const float*)d_in[0];
  const float* x2     = (const float*)d_in[1];
  const float* conv_w = (const float*)d_in[2];
  const float* conv_b = (const float*)d_in[3];
  const float* wq     = (const float*)d_in[4];
  const float* wk     = (const float*)d_in[5];
  const float* wv     = (const float*)d_in[6];
  const float* proj_w = (const float*)d_in[7];
  const float* proj_b = (const float*)d_in[8];
  float* out = (float*)d_out;

  char* ws = (char*)d_ws;
  size_t off = 0;
  auto alloc = [&](size_t bytes) -> void* {
    void* p = ws + off;
    off += (bytes + 255) & ~(size_t)255;
    return p;
  };
  u16* x1b  = (u16*)alloc(8192ULL * 1024 * 2);
  u16* in_t = (u16*)alloc(8ULL * 1024 * 2048 * 2);
  u16* Wp   = (u16*)alloc(9ULL * 2097152 * 2);
  u16* wqb  = (u16*)alloc(1048576ULL * 2);
  u16* wkb  = (u16*)alloc(1048576ULL * 2);
  u16* wvb  = (u16*)alloc(1048576ULL * 2);
  u16* pjb  = (u16*)alloc(1048576ULL * 2);
  u16* xc   = (u16*)alloc(8192ULL * 1024 * 2);
  u16* Qb   = (u16*)alloc(8192ULL * 1024 * 2);
  u16* Kb   = (u16*)alloc(8192ULL * 1024 * 2);
  u16* Vtb  = (u16*)alloc(8192ULL * 1024 * 2);
  u16* Ob   = (u16*)alloc(8192ULL * 1024 * 2);
  u16* zb   = (u16*)alloc(256);

  // prep
  cast_k<<<8192, 256, 0, stream>>>(x1, x1b, 2097152);
  cast_k<<<1024, 256, 0, stream>>>(wq, wqb, 262144);
  cast_k<<<1024, 256, 0, stream>>>(wk, wkb, 262144);
  cast_k<<<1024, 256, 0, stream>>>(wv, wvb, 262144);
  cast_k<<<1024, 256, 0, stream>>>(proj_w, pjb, 262144);
  build_int<<<dim3(32, 16, 8), 256, 0, stream>>>(x1, x2, in_t);
  pack_wp<<<8192, 256, 0, stream>>>(conv_w, Wp);
  zero_k<<<1, 128, 0, stream>>>(zb);

  // conv as implicit GEMM (9 shifted planes over K=18432)
  gemm2_k<GM_CONV><<<512, 512, 0, stream>>>(in_t, Wp, xc, nullptr, conv_b, nullptr, zb, 18432);
  // Q/K/V
  gemm2_k<GM_PLAIN><<<512, 512, 0, stream>>>(x1b, wqb, Qb, nullptr, nullptr, nullptr, zb, 1024);
  gemm2_k<GM_PLAIN><<<512, 512, 0, stream>>>(xc, wkb, Kb, nullptr, nullptr, nullptr, zb, 1024);
  gemm2_k<GM_VT><<<512, 512, 0, stream>>>(xc, wvb, Vtb, nullptr, nullptr, nullptr, zb, 1024);
  // attention
  attn_k<<<dim3(16, 64), 256, 0, stream>>>(Qb, Kb, Vtb, Ob);
  // projection + bias + residual (f32 out)
  gemm2_k<GM_PROJ><<<512, 512, 0, stream>>>(Ob, pjb, nullptr, out, proj_b, x1, zb, 1024);
}

// Round 3
// 591.840 us; speedup vs baseline: 1.2966x; 1.1043x over previous
//
#include <hip/hip_runtime.h>
#include <hip/hip_bf16.h>
#include <cstdint>
#include <cstddef>

typedef __attribute__((ext_vector_type(8))) short short8;
typedef __attribute__((ext_vector_type(4))) float f32x4;
typedef unsigned short u16;

static __device__ __forceinline__ u16 f2bf(float f) {
  __hip_bfloat16 h = __float2bfloat16(f);
  return *reinterpret_cast<u16*>(&h);
}

static __device__ __forceinline__ void gload16(const void* g, void* l) {
  __builtin_amdgcn_global_load_lds(
      (const __attribute__((address_space(1))) void*)g,
      (__attribute__((address_space(3))) void*)l, 16, 0, 0);
}

// ---------------- prep kernels ----------------

__global__ void cast_k(const float* __restrict__ in, u16* __restrict__ out, int n4) {
  int i = blockIdx.x * 256 + threadIdx.x;
  if (i < n4) {
    float4 v = ((const float4*)in)[i];
    union { u16 u[4]; uint2 p; } r;
    r.u[0] = f2bf(v.x); r.u[1] = f2bf(v.y); r.u[2] = f2bf(v.z); r.u[3] = f2bf(v.w);
    ((uint2*)out)[i] = r.p;
  }
}

// in_t[b][s][i] = bf16( concat(x1,x2)[b][i][s] ), i in [0,2048)
__global__ void build_int(const float* __restrict__ x1, const float* __restrict__ x2,
                          u16* __restrict__ in_t) {
  __shared__ float tile[64][65];
  const int it = blockIdx.x;   // 32 i-tiles
  const int st = blockIdx.y;   // 16 s-tiles
  const int b  = blockIdx.z;   // 8
  const int i0 = it * 64, s0 = st * 64;
  const float* src = (i0 < 1024)
      ? x1 + ((size_t)b * 1024 + i0) * 1024
      : x2 + ((size_t)b * 1024 + (i0 - 1024)) * 1024;
  const int t = threadIdx.x;
  #pragma unroll
  for (int jj = 0; jj < 16; ++jj) {
    int idx = jj * 256 + t;
    int ii = idx >> 6, si = idx & 63;
    tile[ii][si] = src[(size_t)ii * 1024 + s0 + si];
  }
  __syncthreads();
  #pragma unroll
  for (int jj = 0; jj < 16; ++jj) {
    int idx = jj * 256 + t;
    int si = idx >> 6, ii = idx & 63;
    in_t[((size_t)b * 1024 + s0 + si) * 2048 + i0 + ii] = f2bf(tile[ii][si]);
  }
}

// Wp[q][o][i] = bf16( conv_w[o][i][q] ),  q = ky*3+kx
__global__ void pack_wp(const float* __restrict__ cw, u16* __restrict__ Wp) {
  __shared__ float sb[2304];
  const int blk = blockIdx.x;  // 8192
  const int t = threadIdx.x;   // 256
  const size_t base = (size_t)blk * 2304;
  #pragma unroll
  for (int jj = 0; jj < 9; ++jj) sb[jj * 256 + t] = cw[base + jj * 256 + t];
  __syncthreads();
  const int p = blk * 256 + t;  // (o,i) linear
  #pragma unroll
  for (int q = 0; q < 9; ++q)
    Wp[(size_t)q * 2097152 + p] = f2bf(sb[t * 9 + q]);
}

__global__ void zero_k(u16* z) { z[threadIdx.x] = 0; }

// ---------------- pipelined GEMM (C = A @ B^T), 256x128 tile, BK=64 ----------------
// 512 threads = 8 waves (4M x 2N), wave tile 64x64 (acc 4x4 -> LDS-read/FLOP ratio
// 1/32 vs 3/64 before). Triple-buffered LDS (144 KiB), counted vmcnt(6) (T3+T4),
// XOR-swizzled LDS granules (T2, rule #21), setprio on MFMA (T5), T1 XCD chunking.

enum { GM_PLAIN = 0, GM_VT = 1, GM_PROJ = 2, GM_CONV = 3 };

template<int MODE>
__global__ __launch_bounds__(512, 2)
void gemm3_k(const u16* __restrict__ A, const u16* __restrict__ B,
             u16* __restrict__ Cb, float* __restrict__ Cf,
             const float* __restrict__ bias, const float* __restrict__ resid,
             const u16* __restrict__ zb, int Ktot) {
  // per buffer: A 256x64 (16384 u16) + B 128x64 (8192 u16) = 24576 u16 (48 KB)
  __shared__ u16 lds[3 * 24576];
  const int tid = threadIdx.x;
  const int lane = tid & 63;
  const int w = tid >> 6;
  const int l15 = lane & 15, l4 = lane >> 4;

  // T1: chunked XCD remap (nwg=256, 256%8==0 -> bijective)
  const int bid = blockIdx.x;
  const int lb = (bid & 7) * 32 + (bid >> 3);
  const int tm = lb >> 3, tn = lb & 7;
  const int row0 = tm * 256, col0 = tn * 128;
  const int wr = (w >> 1) * 64, wc = (w & 1) * 64;

  // staging geometry: sweep u covers rows u*64 + sr; 16B-granule p' inverse-swizzled
  const int sr = w * 8 + (lane >> 3);
  const int pp = (lane & 7) ^ (lane >> 3);

  // conv A-row precompute (A row = row0 + u*64 + sr, u=0..3)
  int am[4], ay[4], ax[4];
  #pragma unroll
  for (int u = 0; u < 4; ++u) {
    const int m = row0 + u * 64 + sr;
    am[u] = m;
    const int s = m & 1023;
    ay[u] = s >> 5; ax[u] = s & 31;
  }

  f32x4 acc[4][4];
  #pragma unroll
  for (int i = 0; i < 4; ++i)
    #pragma unroll
    for (int jj = 0; jj < 4; ++jj)
      acc[i][jj] = (f32x4){0.f, 0.f, 0.f, 0.f};

  const int nK = Ktot >> 6;

  auto stage = [&](int kt, u16* buf) {
    u16* da = buf + (size_t)w * 512;           // + u*4096 below (A: 4 sweeps)
    u16* db = buf + 16384 + (size_t)w * 512;   // + u*4096 below (B: 2 sweeps)
    if constexpr (MODE == GM_CONV) {
      const int q = kt >> 5;                   // offset plane 0..8
      const int ks = (kt & 31) << 6;
      const int qd = (q >= 6) ? 2 : (q >= 3) ? 1 : 0;
      const int dy = qd - 1, dx = q - qd * 3 - 1;
      const int dd = (dy << 5) + dx;
      #pragma unroll
      for (int u = 0; u < 4; ++u) {
        const int yy = ay[u] + dy, xx = ax[u] + dx;
        const bool valid = ((unsigned)yy < 32u) && ((unsigned)xx < 32u);
        const u16* ga = valid ? A + (((size_t)(am[u] + dd)) << 11) + ks + pp * 8 : zb;
        gload16(ga, da + u * 4096);
      }
      const size_t boff = ((size_t)q << 21) + ks + pp * 8;
      #pragma unroll
      for (int u = 0; u < 2; ++u) {
        const u16* gb = B + boff + ((size_t)(col0 + u * 64 + sr) << 11);
        gload16(gb, db + u * 4096);
      }
    } else {
      const int k0 = kt << 6;
      #pragma unroll
      for (int u = 0; u < 4; ++u) {
        const u16* ga = A + (size_t)(row0 + u * 64 + sr) * Ktot + k0 + pp * 8;
        gload16(ga, da + u * 4096);
      }
      #pragma unroll
      for (int u = 0; u < 2; ++u) {
        const u16* gb = B + (size_t)(col0 + u * 64 + sr) * Ktot + k0 + pp * 8;
        gload16(gb, db + u * 4096);
      }
    }
  };

  auto compute = [&](const u16* buf) {
    const char* Ar = (const char*)buf;
    const char* Br = (const char*)(buf + 16384);
    #pragma unroll
    for (int ks = 0; ks < 2; ++ks) {
      const int bcol = ((ks << 6) + (l4 << 4)) ^ ((l15 & 7) << 4);
      short8 av[4], bv[4];
      #pragma unroll
      for (int mi = 0; mi < 4; ++mi)
        av[mi] = *(const short8*)(Ar + (wr + mi * 16 + l15) * 128 + bcol);
      #pragma unroll
      for (int ni = 0; ni < 4; ++ni)
        bv[ni] = *(const short8*)(Br + (wc + ni * 16 + l15) * 128 + bcol);
      __builtin_amdgcn_s_setprio(1);
      #pragma unroll
      for (int mi = 0; mi < 4; ++mi)
        #pragma unroll
        for (int ni = 0; ni < 4; ++ni)
          acc[mi][ni] = __builtin_amdgcn_mfma_f32_16x16x32_bf16(av[mi], bv[ni], acc[mi][ni], 0, 0, 0);
      __builtin_amdgcn_s_setprio(0);
    }
  };

  u16* pb0 = lds;
  u16* pb1 = lds + 24576;
  u16* pb2 = lds + 49152;

  stage(0, pb0);
  stage(1, pb1);
  for (int t = 0; t < nK; ++t) {
    if (t + 1 < nK) {
      asm volatile("s_waitcnt vmcnt(6)" ::: "memory");
    } else {
      asm volatile("s_waitcnt vmcnt(0)" ::: "memory");
    }
    __builtin_amdgcn_s_barrier();
    if (t + 2 < nK) stage(t + 2, pb2);
    compute(pb0);
    u16* tmp = pb0; pb0 = pb1; pb1 = pb2; pb2 = tmp;
  }

  // epilogue: D layout col=lane&15, row=(lane>>4)*4+j
  #pragma unroll
  for (int mi = 0; mi < 4; ++mi) {
    #pragma unroll
    for (int ni = 0; ni < 4; ++ni) {
      #pragma unroll
      for (int j = 0; j < 4; ++j) {
        const int grow = row0 + wr + mi * 16 + l4 * 4 + j;
        const int gcol = col0 + wc + ni * 16 + l15;
        const float v = acc[mi][ni][j];
        if constexpr (MODE == GM_PLAIN) {
          Cb[((size_t)grow << 10) + gcol] = f2bf(v);
        } else if constexpr (MODE == GM_VT) {
          const int b = grow >> 10, ms = grow & 1023;
          const int h = gcol >> 7, d = gcol & 127;
          Cb[((size_t)((b * 8 + h) * 128 + d) << 10) + ms] = f2bf(v);
        } else if constexpr (MODE == GM_PROJ) {
          const size_t o = ((size_t)grow << 10) + gcol;
          Cf[o] = v + bias[gcol] + resid[o];
        } else {  // GM_CONV: xc[b][o][s]  (tokens are conv channels, features spatial)
          const int b = grow >> 10, s = grow & 1023;
          Cb[((size_t)((b << 10) + gcol) << 10) + s] = f2bf(v + bias[gcol]);
        }
      }
    }
  }
}

// ---------------- flash attention ----------------
// grid (16 mtiles, 64 bh). 4 waves; wave w owns Q rows [w*16, w*16+16).
__global__ __launch_bounds__(256, 2)
void attn_k(const u16* __restrict__ Q, const u16* __restrict__ K,
            const u16* __restrict__ Vt, u16* __restrict__ O) {
  __shared__ u16 Ks[64 * 128];
  __shared__ u16 Vs[128 * 64];
  __shared__ u16 Plds[4][16 * 80];
  const int mtile = blockIdx.x;
  const int bh = blockIdx.y;
  const int b = bh >> 3, h = bh & 7;
  const int tid = threadIdx.x, lane = tid & 63, w = tid >> 6;
  const int l15 = lane & 15, l4 = lane >> 4;

  short8 qf[4];
  {
    const int qrow = b * 1024 + mtile * 64 + w * 16 + l15;
    const u16* qb = Q + ((size_t)qrow << 10) + h * 128;
    #pragma unroll
    for (int kk = 0; kk < 4; ++kk)
      qf[kk] = *(const short8*)(qb + kk * 32 + l4 * 8);
  }

  f32x4 o[8];
  #pragma unroll
  for (int db = 0; db < 8; ++db) o[db] = (f32x4){0.f, 0.f, 0.f, 0.f};
  float mrow[4], lrow[4];
  #pragma unroll
  for (int j = 0; j < 4; ++j) { mrow[j] = -1e30f; lrow[j] = 0.f; }
  const float scale = 0.08838834764831845f;  // 128^-0.5

  for (int kt = 0; kt < 16; ++kt) {
    __syncthreads();
    #pragma unroll
    for (int j = 0; j < 4; ++j) {
      const int c = (j * 4 + w) * 64 + lane;
      const int r = c >> 4, coff = (c & 15) << 3;
      const u16* gp = K + ((size_t)(b * 1024 + kt * 64 + r) << 10) + h * 128 + coff;
      gload16(gp, (void*)(Ks + (j * 4 + w) * 512));
    }
    #pragma unroll
    for (int j = 0; j < 4; ++j) {
      const int c = (j * 4 + w) * 64 + lane;
      const int r = c >> 3, coff = (c & 7) << 3;
      const u16* gp = Vt + ((size_t)((b * 8 + h) * 128 + r) << 10) + kt * 64 + coff;
      gload16(gp, (void*)(Vs + (j * 4 + w) * 512));
    }
    __syncthreads();
    f32x4 s[4];
    #pragma unroll
    for (int cb = 0; cb < 4; ++cb) {
      s[cb] = (f32x4){0.f, 0.f, 0.f, 0.f};
      #pragma unroll
      for (int kk = 0; kk < 4; ++kk) {
        short8 bK = *(const short8*)(Ks + (cb * 16 + l15) * 128 + kk * 32 + l4 * 8);
        s[cb] = __builtin_amdgcn_mfma_f32_16x16x32_bf16(qf[kk], bK, s[cb], 0, 0, 0);
      }
    }
    #pragma unroll
    for (int cb = 0; cb < 4; ++cb) {
      s[cb][0] *= scale; s[cb][1] *= scale; s[cb][2] *= scale; s[cb][3] *= scale;
    }
    #pragma unroll
    for (int j = 0; j < 4; ++j) {
      float mx = fmaxf(fmaxf(s[0][j], s[1][j]), fmaxf(s[2][j], s[3][j]));
      #pragma unroll
      for (int off = 8; off >= 1; off >>= 1)
        mx = fmaxf(mx, __shfl_xor(mx, off, 64));
      const float mn = fmaxf(mrow[j], mx);
      const float fac = __expf(mrow[j] - mn);
      mrow[j] = mn;
      float rs = 0.f;
      #pragma unroll
      for (int cb = 0; cb < 4; ++cb) {
        const float p = __expf(s[cb][j] - mn);
        s[cb][j] = p;
        rs += p;
      }
      #pragma unroll
      for (int off = 8; off >= 1; off >>= 1)
        rs += __shfl_xor(rs, off, 64);
      lrow[j] = lrow[j] * fac + rs;
      #pragma unroll
      for (int db = 0; db < 8; ++db) o[db][j] *= fac;
    }
    u16* pl = Plds[w];
    #pragma unroll
    for (int cb = 0; cb < 4; ++cb)
      #pragma unroll
      for (int j = 0; j < 4; ++j)
        pl[(l4 * 4 + j) * 80 + cb * 16 + l15] = f2bf(s[cb][j]);
    __syncthreads();
    short8 ap[2];
    #pragma unroll
    for (int ks = 0; ks < 2; ++ks)
      ap[ks] = *(const short8*)(pl + l15 * 80 + ks * 32 + l4 * 8);
    #pragma unroll
    for (int db = 0; db < 8; ++db) {
      #pragma unroll
      for (int ks = 0; ks < 2; ++ks) {
        short8 bV = *(const short8*)(Vs + (db * 16 + l15) * 64 + ks * 32 + l4 * 8);
        o[db] = __builtin_amdgcn_mfma_f32_16x16x32_bf16(ap[ks], bV, o[db], 0, 0, 0);
      }
    }
  }
  #pragma unroll
  for (int db = 0; db < 8; ++db) {
    #pragma unroll
    for (int j = 0; j < 4; ++j) {
      const int grow = b * 1024 + mtile * 64 + w * 16 + l4 * 4 + j;
      const int gcol = h * 128 + db * 16 + l15;
      O[((size_t)grow << 10) + gcol] = f2bf(o[db][j] / lrow[j]);
    }
  }
}

// ---------------- launch ----------------

extern "C" void kernel_launch(void* const* d_in, const int* in_sizes, int n_in,
                              void* d_out, int out_size, void* d_ws, size_t ws_size,
                              hipStream_t stream) {
  const float* x1     = (const float*)d_in[0];
  const float* x2     = (const float*)d_in[1];
  const float* conv_w = (const float*)d_in[2];
  const float* conv_b = (const float*)d_in[3];
  const float* wq     = (const float*)d_in[4];
  const float* wk     = (const float*)d_in[5];
  const float* wv     = (const float*)d_in[6];
  const float* proj_w = (const float*)d_in[7];
  const float* proj_b = (const float*)d_in[8];
  float* out = (float*)d_out;

  char* ws = (char*)d_ws;
  size_t off = 0;
  auto alloc = [&](size_t bytes) -> void* {
    void* p = ws + off;
    off += (bytes + 255) & ~(size_t)255;
    return p;
  };
  u16* x1b  = (u16*)alloc(8192ULL * 1024 * 2);
  u16* in_t = (u16*)alloc(8ULL * 1024 * 2048 * 2);
  u16* Wp   = (u16*)alloc(9ULL * 2097152 * 2);
  u16* wqb  = (u16*)alloc(1048576ULL * 2);
  u16* wkb  = (u16*)alloc(1048576ULL * 2);
  u16* wvb  = (u16*)alloc(1048576ULL * 2);
  u16* pjb  = (u16*)alloc(1048576ULL * 2);
  u16* xc   = (u16*)alloc(8192ULL * 1024 * 2);
  u16* Qb   = (u16*)alloc(8192ULL * 1024 * 2);
  u16* Kb   = (u16*)alloc(8192ULL * 1024 * 2);
  u16* Vtb  = (u16*)alloc(8192ULL * 1024 * 2);
  u16* Ob   = (u16*)alloc(8192ULL * 1024 * 2);
  u16* zb   = (u16*)alloc(256);

  // prep
  cast_k<<<8192, 256, 0, stream>>>(x1, x1b, 2097152);
  cast_k<<<1024, 256, 0, stream>>>(wq, wqb, 262144);
  cast_k<<<1024, 256, 0, stream>>>(wk, wkb, 262144);
  cast_k<<<1024, 256, 0, stream>>>(wv, wvb, 262144);
  cast_k<<<1024, 256, 0, stream>>>(proj_w, pjb, 262144);
  build_int<<<dim3(32, 16, 8), 256, 0, stream>>>(x1, x2, in_t);
  pack_wp<<<8192, 256, 0, stream>>>(conv_w, Wp);
  zero_k<<<1, 128, 0, stream>>>(zb);

  // conv as implicit GEMM (9 shifted planes over K=18432)
  gemm3_k<GM_CONV><<<256, 512, 0, stream>>>(in_t, Wp, xc, nullptr, conv_b, nullptr, zb, 18432);
  // Q/K/V
  gemm3_k<GM_PLAIN><<<256, 512, 0, stream>>>(x1b, wqb, Qb, nullptr, nullptr, nullptr, zb, 1024);
  gemm3_k<GM_PLAIN><<<256, 512, 0, stream>>>(xc, wkb, Kb, nullptr, nullptr, nullptr, zb, 1024);
  gemm3_k<GM_VT><<<256, 512, 0, stream>>>(xc, wvb, Vtb, nullptr, nullptr, nullptr, zb, 1024);
  // attention
  attn_k<<<dim3(16, 64), 256, 0, stream>>>(Qb, Kb, Vtb, Ob);
  // projection + bias + residual (f32 out)
  gemm3_k<GM_PROJ><<<256, 512, 0, stream>>>(Ob, pjb, nullptr, out, proj_b, x1, zb, 1024);
}